// Round 4
// baseline (1137.436 us; speedup 1.0000x reference)
//
#include <hip/hip_runtime.h>
#include <stdint.h>

#define HH 256
#define WW 256
#define CIN 64
#define NPIX 65536
#define TW 64
#define TH 16
#define NCELL 1188    // 66*18 halo cells
#define NCELLP 1216   // kernel-1 padding (multiple of 64)
#define NCELLP2 1196  // kernel-2 padding (frees 8KB LDS for wh frags)

typedef uint32_t u32;
typedef __attribute__((ext_vector_type(4))) float f32x4;
typedef __attribute__((ext_vector_type(8))) short short8;

union FR { u32 u[4]; short8 s; };

__device__ __forceinline__ int refl(int t, int n) {
    if (t < 0) return -t;
    if (t >= n) return 2 * n - 2 - t;
    return t;
}

__device__ __forceinline__ void gload_lds4(const float* g, float* l) {
    __builtin_amdgcn_global_load_lds(
        (const __attribute__((address_space(1))) u32*)g,
        (__attribute__((address_space(3))) u32*)l, 4, 0, 0);
}

__device__ __forceinline__ u32 bfpack(float a, float b) {
    u32 ua = __float_as_uint(a), ub = __float_as_uint(b);
    ua = (ua + 0x7fffu + ((ua >> 16) & 1u)) >> 16;
    ub = (ub + 0x7fffu + ((ub >> 16) & 1u)) & 0xffff0000u;
    return ua | ub;
}
__device__ __forceinline__ float bflo(u32 v) { return __uint_as_float(v << 16); }
__device__ __forceinline__ float bfhi(u32 v) { return __uint_as_float(v & 0xffff0000u); }

// truncating bf16 pair pack: lo16 = bf16(a), hi16 = bf16(b)
__device__ __forceinline__ u32 pack2t(float a, float b) {
    return (__float_as_uint(a) >> 16) | (__float_as_uint(b) & 0xffff0000u);
}
__device__ __forceinline__ float bftrunc(float a) {
    return __uint_as_float(__float_as_uint(a) & 0xffff0000u);
}

// ---------------------------------------------------------------------------
// Kernel 1: softmax attention weights w9[n][9][H][W]   (UNCHANGED)
// ---------------------------------------------------------------------------
__global__ __launch_bounds__(512, 4)
void san_weights(const float* __restrict__ x,
                 const float* __restrict__ w1, const float* __restrict__ b1,
                 const float* __restrict__ w2, const float* __restrict__ b2,
                 const float* __restrict__ cpw,
                 const float* __restrict__ bn1g, const float* __restrict__ bn1b,
                 const float* __restrict__ bn1m, const float* __restrict__ bn1v,
                 const float* __restrict__ wmid,
                 const float* __restrict__ bn2g, const float* __restrict__ bn2b,
                 const float* __restrict__ bn2m, const float* __restrict__ bn2v,
                 const float* __restrict__ wout, const float* __restrict__ bout,
                 float* __restrict__ w9)
{
    __shared__ float stage[8 * NCELLP];   // 38912 B
    __shared__ uint4 x2l[NCELL];          // 19008 B (8 bf16 per cell)
    __shared__ uint4 x1l[TW * TH];        // 16384 B

    const int n = blockIdx.z;
    const int ty = blockIdx.y * TH, tx = blockIdx.x * TW;
    const int tid = threadIdx.x;
    const int wave = tid >> 6, lane = tid & 63;
    const float* xn = x + (size_t)n * CIN * NPIX;

    float acc[3][16];
    #pragma unroll
    for (int o = 0; o < 8; ++o) {
        float b = b1[o];
        acc[0][o] = b; acc[1][o] = b; acc[2][o] = b;
    }
    #pragma unroll
    for (int o = 0; o < 8; ++o) {
        float b = b2[o];
        acc[0][8 + o] = b; acc[1][8 + o] = b; acc[2][8 + o] = b;
    }

    const int cA = tid, cB = tid + 512, cC = tid + 1024;
    const int cCc = (cC < NCELL) ? cC : 0;

    for (int c0 = 0; c0 < 64; c0 += 8) {
        if (c0) __syncthreads();   // previous chunk's LDS reads complete
        // stage 8 channels x halo cells (async, direct-to-LDS)
        for (int t = wave; t < 152; t += 8) {
            int cc = t / 19, r = t - cc * 19;
            int cell = r * 64 + lane;
            if (cell < NCELL) {
                int hy = cell / 66, hx = cell - hy * 66;
                int gy = refl(ty + hy - 1, HH), gx = refl(tx + hx - 1, WW);
                gload_lds4(xn + (size_t)(c0 + cc) * NPIX + gy * WW + gx,
                           &stage[cc * NCELLP + r * 64]);
            }
        }
        __syncthreads();           // staging complete (vmcnt drained)

        float xv[3][8];
        #pragma unroll
        for (int j = 0; j < 8; ++j) {
            xv[0][j] = stage[j * NCELLP + cA];
            xv[1][j] = stage[j * NCELLP + cB];
            xv[2][j] = stage[j * NCELLP + cCc];
        }
        #pragma unroll
        for (int o = 0; o < 16; ++o) {
            const float* wr = (o < 8) ? (w1 + o * CIN + c0) : (w2 + (o - 8) * CIN + c0);
            #pragma unroll
            for (int j = 0; j < 8; ++j) {
                float wj = wr[j];
                acc[0][o] = fmaf(wj, xv[0][j], acc[0][o]);
                acc[1][o] = fmaf(wj, xv[1][j], acc[1][o]);
                acc[2][o] = fmaf(wj, xv[2][j], acc[2][o]);
            }
        }
    }

    // write x1 (interior only) / x2 (all halo cells) to LDS as bf16
    #pragma unroll
    for (int ci = 0; ci < 3; ++ci) {
        int cell = tid + ci * 512;
        if (cell < NCELL) {
            uint4 v2;
            v2.x = bfpack(acc[ci][8],  acc[ci][9]);
            v2.y = bfpack(acc[ci][10], acc[ci][11]);
            v2.z = bfpack(acc[ci][12], acc[ci][13]);
            v2.w = bfpack(acc[ci][14], acc[ci][15]);
            x2l[cell] = v2;
            int hy = cell / 66, hx = cell - hy * 66;
            if (hy >= 1 && hy <= TH && hx >= 1 && hx <= TW) {
                uint4 v1;
                v1.x = bfpack(acc[ci][0], acc[ci][1]);
                v1.y = bfpack(acc[ci][2], acc[ci][3]);
                v1.z = bfpack(acc[ci][4], acc[ci][5]);
                v1.w = bfpack(acc[ci][6], acc[ci][7]);
                x1l[(hy - 1) * TW + (hx - 1)] = v1;
            }
        }
    }
    __syncthreads();

    // fold BN params
    float s1[10], o1[10];
    #pragma unroll
    for (int c = 0; c < 10; ++c) {
        float s = bn1g[c] * rsqrtf(bn1v[c] + 1e-5f);
        s1[c] = s;
        o1[c] = bn1b[c] - bn1m[c] * s;
    }
    float s2[8], o2[8];
    #pragma unroll
    for (int e = 0; e < 8; ++e) {
        float s = bn2g[e] * rsqrtf(bn2v[e] + 1e-5f);
        s2[e] = s;
        o2[e] = bn2b[e] - bn2m[e] * s;
    }
    const float cp00 = cpw[0], cp01 = cpw[1], cp10 = cpw[2], cp11 = cpw[3];
    const float bo = bout[0];

    // MLP + softmax, 2 pixels per thread
    #pragma unroll
    for (int pi = 0; pi < 2; ++pi) {
        int px = tid + pi * 512;
        int py = px >> 6, pxx = px & 63;
        int h = ty + py, w = tx + pxx;
        int cell = (py + 1) * 66 + (pxx + 1);
        uint4 v1 = x1l[px];
        float x1v[8];
        x1v[0] = bflo(v1.x); x1v[1] = bfhi(v1.x);
        x1v[2] = bflo(v1.y); x1v[3] = bfhi(v1.y);
        x1v[4] = bflo(v1.z); x1v[5] = bfhi(v1.z);
        x1v[6] = bflo(v1.w); x1v[7] = bfhi(v1.w);
        float lg[9];
        #pragma unroll
        for (int k = 0; k < 9; ++k) {
            int dy = k / 3 - 1, dx = k % 3 - 1;
            uint4 v2 = x2l[cell + dy * 66 + dx];
            float f[10];
            f[0] = x1v[0] - bflo(v2.x); f[1] = x1v[1] - bfhi(v2.x);
            f[2] = x1v[2] - bflo(v2.y); f[3] = x1v[3] - bfhi(v2.y);
            f[4] = x1v[4] - bflo(v2.z); f[5] = x1v[5] - bfhi(v2.z);
            f[6] = x1v[6] - bflo(v2.w); f[7] = x1v[7] - bfhi(v2.w);
            int hn = refl(h + dy, HH), wn = refl(w + dx, WW);
            float dp0 = (2.0f / 255.0f) * (float)(w - wn);
            float dp1 = (2.0f / 255.0f) * (float)(h - hn);
            f[8] = cp00 * dp0 + cp01 * dp1;
            f[9] = cp10 * dp0 + cp11 * dp1;
            float a[10];
            #pragma unroll
            for (int c = 0; c < 10; ++c)
                a[c] = fmaxf(fmaf(f[c], s1[c], o1[c]), 0.0f);
            float lgk = bo;
            #pragma unroll
            for (int e = 0; e < 8; ++e) {
                float g = 0.0f;
                #pragma unroll
                for (int c = 0; c < 10; ++c) g = fmaf(wmid[e * 10 + c], a[c], g);
                g = fmaxf(fmaf(g, s2[e], o2[e]), 0.0f);
                lgk = fmaf(wout[e], g, lgk);
            }
            lg[k] = lgk;
        }
        float m = lg[0];
        #pragma unroll
        for (int k = 1; k < 9; ++k) m = fmaxf(m, lg[k]);
        float e9[9], ssum = 0.0f;
        #pragma unroll
        for (int k = 0; k < 9; ++k) { e9[k] = __expf(lg[k] - m); ssum += e9[k]; }
        float inv = 1.0f / ssum;
        size_t base = (size_t)n * 9 * NPIX + (size_t)h * WW + w;
        #pragma unroll
        for (int k = 0; k < 9; ++k) w9[base + (size_t)k * NPIX] = e9[k] * inv;
    }
}

// ---------------------------------------------------------------------------
// Kernel 2: s_c = sum_k w_k * x_c[p+dk]; out = W3 @ s + b3
// MFMA split-bf16 channel mix (exact: wh@[sh;sl] + wl@[sh;sl]).
// Register diet vs round 2 (which spilled to scratch at the 128-reg/wave
// budget: FETCH/WRITE blowup): wk2 bf16-packed (18->9 regs), only 2 B-frag
// pixel-groups live at once (16->8 regs), whf as uint4 (b128 reads, kills
// the 8-way bank conflict on the old b32 stride-16B pattern).
// ---------------------------------------------------------------------------
__global__ __launch_bounds__(1024, 4)
void san_agg(const float* __restrict__ x, const float* __restrict__ w9,
             const float* __restrict__ w3, const float* __restrict__ b3,
             float* __restrict__ out)
{
    __shared__ float buf[2][16 * NCELLP2];  // 2 x 76544 B = 153088 B
    __shared__ uint4 whf[4][4][32];         // [chunk][mt][l2] = 8192 B

    const int nb = blockIdx.z;
    const int ty = blockIdx.y * TH, tx = blockIdx.x * TW;
    const int tid = threadIdx.x;
    const int wave = tid >> 6, lane = tid & 63;
    const int q = lane >> 4, nn = lane & 15;
    const int oct = q & 1;        // which 8-channel octet of the chunk this lane owns
    const int half = lane >> 5;   // 0: owns even pixel-group, 1: odd
    const float* xn = x + (size_t)nb * CIN * NPIX;

    auto stage = [&](int ch0, int b) {
        for (int t = wave; t < 304; t += 16) {
            int cc = t / 19, r = t - cc * 19;
            int cell = r * 64 + lane;
            if (cell < NCELL) {
                int hy = cell / 66, hx = cell - hy * 66;
                int gy = refl(ty + hy - 1, HH), gx = refl(tx + hx - 1, WW);
                gload_lds4(xn + (size_t)(ch0 + cc) * NPIX + gy * WW + gx,
                           &buf[b][cc * NCELLP2 + r * 64]);
            }
        }
    };

    stage(0, 0);

    // pre-pack wh A-fragments as uint4: entry [kc][mt][l2] covers
    // row m = mt*16 + (l2&15), cols kc*16 + (l2>>4)*8 + {0..7} (pairs per r)
    if (tid < 512) {
        int kcp = tid >> 7, mtp = (tid >> 5) & 3, l2 = tid & 31;
        int m = mtp * 16 + (l2 & 15);
        int c0 = kcp * 16 + (l2 >> 4) * 8;
        const float* wr = w3 + m * 64 + c0;
        float4 wa = *(const float4*)wr;
        float4 wb = *(const float4*)(wr + 4);
        uint4 e;
        e.x = pack2t(wa.x, wa.y); e.y = pack2t(wa.z, wa.w);
        e.z = pack2t(wb.x, wb.y); e.w = pack2t(wb.z, wb.w);
        whf[kcp][mtp][l2] = e;
    }

    // attention weights for the 2 owned pixels, bf16-packed (lo=s0, hi=s1)
    u32 wk2p[9];
    int cellc[2];
    {
        const int h = ty + wave;
        int xw0 = half * 16 + nn;          // s = 0 pixel
        int xw1 = (2 + half) * 16 + nn;    // s = 1 pixel
        cellc[0] = (wave + 1) * 66 + xw0 + 1;
        cellc[1] = (wave + 1) * 66 + xw1 + 1;
        size_t wb = (size_t)nb * 9 * NPIX + (size_t)h * WW + tx;
        #pragma unroll
        for (int k = 0; k < 9; ++k)
            wk2p[k] = bfpack(w9[wb + (size_t)k * NPIX + xw0],
                             w9[wb + (size_t)k * NPIX + xw1]);
    }

    // accumulators: C row = q*4+j (out channel within mt), col = nn (pixel)
    f32x4 acc[4][4];
    #pragma unroll
    for (int mt = 0; mt < 4; ++mt) {
        #pragma unroll
        for (int j = 0; j < 4; ++j) {
            float bv = b3[mt * 16 + q * 4 + j];
            acc[mt][0][j] = bv; acc[mt][1][j] = bv;
            acc[mt][2][j] = bv; acc[mt][3][j] = bv;
        }
    }

    __syncthreads();   // chunk 0 staged, whf ready

    for (int kc = 0; kc < 4; ++kc) {
        if (kc < 3) stage((kc + 1) * 16, (kc + 1) & 1);
        const float* bp = buf[kc & 1];

        #pragma unroll
        for (int s = 0; s < 2; ++s) {
            float wkf[9];
            #pragma unroll
            for (int k = 0; k < 9; ++k)
                wkf[k] = (s == 0) ? bflo(wk2p[k]) : bfhi(wk2p[k]);

            // 9-tap aggregation for this lane's 8 channels, pixel group 2s+half
            const float* cb = bp + oct * 8 * NCELLP2 + cellc[s];
            float sv[8];
            #pragma unroll
            for (int j = 0; j < 8; ++j) {
                const float* p = cb + j * NCELLP2;
                float t = wkf[0] * p[-67];
                t = fmaf(wkf[1], p[-66], t);
                t = fmaf(wkf[2], p[-65], t);
                t = fmaf(wkf[3], p[-1],  t);
                t = fmaf(wkf[4], p[0],   t);
                t = fmaf(wkf[5], p[1],   t);
                t = fmaf(wkf[6], p[65],  t);
                t = fmaf(wkf[7], p[66],  t);
                t = fmaf(wkf[8], p[67],  t);
                sv[j] = t;
            }

            // B-fragments for pixel groups 2s and 2s+1: K=32 = [sh(16ch); sl(16ch)]
            u32 frag2[2][4];
            #pragma unroll
            for (int r = 0; r < 4; ++r) {
                float a = sv[2 * r], b = sv[2 * r + 1];
                u32 sh = pack2t(a, b);
                u32 sl = pack2t(a - bftrunc(a), b - bftrunc(b));
                u32 shx = __shfl_xor(sh, 32);
                u32 slx = __shfl_xor(sl, 32);
                frag2[0][r] = (half == 0) ? sh  : slx;  // pixel group 2s
                frag2[1][r] = (half == 0) ? shx : sl;   // pixel group 2s+1
            }

            // channel mix on matrix cores
            #pragma unroll
            for (int mt = 0; mt < 4; ++mt) {
                uint4 whv = whf[kc][mt][lane & 31];
                FR wh;
                wh.u[0] = whv.x; wh.u[1] = whv.y; wh.u[2] = whv.z; wh.u[3] = whv.w;
                const float* wrow = w3 + (mt * 16 + nn) * 64 + kc * 16 + oct * 8;
                FR wl;
                #pragma unroll
                for (int r = 0; r < 4; ++r) {
                    float a = wrow[2 * r], b = wrow[2 * r + 1];
                    wl.u[r] = pack2t(a - bftrunc(a), b - bftrunc(b));
                }
                #pragma unroll
                for (int h2 = 0; h2 < 2; ++h2) {
                    FR bfr;
                    bfr.u[0] = frag2[h2][0]; bfr.u[1] = frag2[h2][1];
                    bfr.u[2] = frag2[h2][2]; bfr.u[3] = frag2[h2][3];
                    acc[mt][2 * s + h2] = __builtin_amdgcn_mfma_f32_16x16x32_bf16(
                        wh.s, bfr.s, acc[mt][2 * s + h2], 0, 0, 0);
                    acc[mt][2 * s + h2] = __builtin_amdgcn_mfma_f32_16x16x32_bf16(
                        wl.s, bfr.s, acc[mt][2 * s + h2], 0, 0, 0);
                }
            }
        }

        if (kc < 3) __syncthreads();   // prefetch landed; buf safe to swap
    }

    // store: channel m = mt*16 + q*4 + j, pixel x = pg*16 + nn, row = wave
    {
        const int h = ty + wave;
        size_t ob = (size_t)nb * CIN * NPIX + (size_t)h * WW + tx;
        #pragma unroll
        for (int mt = 0; mt < 4; ++mt) {
            #pragma unroll
            for (int pg = 0; pg < 4; ++pg) {
                size_t pb = ob + (size_t)pg * 16 + nn;
                #pragma unroll
                for (int j = 0; j < 4; ++j) {
                    int m = mt * 16 + q * 4 + j;
                    out[pb + (size_t)m * NPIX] = acc[mt][pg][j];
                }
            }
        }
    }
}

// ---------------------------------------------------------------------------
extern "C" void kernel_launch(void* const* d_in, const int* in_sizes, int n_in,
                              void* d_out, int out_size, void* d_ws, size_t ws_size,
                              hipStream_t stream) {
    const float* x      = (const float*)d_in[0];
    const float* w1     = (const float*)d_in[1];
    const float* b1     = (const float*)d_in[2];
    const float* w2     = (const float*)d_in[3];
    const float* b2     = (const float*)d_in[4];
    const float* w3     = (const float*)d_in[5];
    const float* b3     = (const float*)d_in[6];
    const float* cpw    = (const float*)d_in[7];
    const float* bn1g   = (const float*)d_in[9];
    const float* bn1b   = (const float*)d_in[10];
    const float* bn1m   = (const float*)d_in[11];
    const float* bn1v   = (const float*)d_in[12];
    const float* wmid   = (const float*)d_in[13];
    const float* bn2g   = (const float*)d_in[14];
    const float* bn2b   = (const float*)d_in[15];
    const float* bn2m   = (const float*)d_in[16];
    const float* bn2v   = (const float*)d_in[17];
    const float* wout   = (const float*)d_in[18];
    const float* bout   = (const float*)d_in[19];
    float* out = (float*)d_out;
    float* w9  = (float*)d_ws;  // 16*9*65536 floats = 37.75 MB

    dim3 grid(WW / TW, HH / TH, 16);
    san_weights<<<grid, 512, 0, stream>>>(x, w1, b1, w2, b2, cpw,
                                          bn1g, bn1b, bn1m, bn1v, wmid,
                                          bn2g, bn2b, bn2m, bn2v, wout, bout, w9);
    san_agg<<<grid, 1024, 0, stream>>>(x, w9, w3, b3, out);
}

// Round 5
// 955.070 us; speedup vs baseline: 1.1909x; 1.1909x over previous
//
#include <hip/hip_runtime.h>
#include <stdint.h>

#define HH 256
#define WW 256
#define CIN 64
#define NPIX 65536
#define TW 64
#define TH 16
#define NCELL 1188    // 66*18 halo cells
#define NCELLP 1216   // kernel-1 padding (multiple of 64)
#define NCELLP2 1196  // kernel-2 padding (12-float bank skew per channel)

typedef uint32_t u32;
typedef __attribute__((ext_vector_type(4))) float f32x4;
typedef __attribute__((ext_vector_type(8))) short short8;

union FR { u32 u[4]; short8 s; };

__device__ __forceinline__ int refl(int t, int n) {
    if (t < 0) return -t;
    if (t >= n) return 2 * n - 2 - t;
    return t;
}

__device__ __forceinline__ void gload_lds4(const float* g, float* l) {
    __builtin_amdgcn_global_load_lds(
        (const __attribute__((address_space(1))) u32*)g,
        (__attribute__((address_space(3))) u32*)l, 4, 0, 0);
}

__device__ __forceinline__ u32 bfpack(float a, float b) {
    u32 ua = __float_as_uint(a), ub = __float_as_uint(b);
    ua = (ua + 0x7fffu + ((ua >> 16) & 1u)) >> 16;
    ub = (ub + 0x7fffu + ((ub >> 16) & 1u)) & 0xffff0000u;
    return ua | ub;
}
__device__ __forceinline__ float bflo(u32 v) { return __uint_as_float(v << 16); }
__device__ __forceinline__ float bfhi(u32 v) { return __uint_as_float(v & 0xffff0000u); }

// truncating bf16 pair pack: lo16 = bf16(a), hi16 = bf16(b)
__device__ __forceinline__ u32 pack2t(float a, float b) {
    return (__float_as_uint(a) >> 16) | (__float_as_uint(b) & 0xffff0000u);
}
__device__ __forceinline__ float bftrunc(float a) {
    return __uint_as_float(__float_as_uint(a) & 0xffff0000u);
}

// ---------------------------------------------------------------------------
// Kernel 1: softmax attention weights w9[n][9][H][W]   (UNCHANGED)
// ---------------------------------------------------------------------------
__global__ __launch_bounds__(512, 4)
void san_weights(const float* __restrict__ x,
                 const float* __restrict__ w1, const float* __restrict__ b1,
                 const float* __restrict__ w2, const float* __restrict__ b2,
                 const float* __restrict__ cpw,
                 const float* __restrict__ bn1g, const float* __restrict__ bn1b,
                 const float* __restrict__ bn1m, const float* __restrict__ bn1v,
                 const float* __restrict__ wmid,
                 const float* __restrict__ bn2g, const float* __restrict__ bn2b,
                 const float* __restrict__ bn2m, const float* __restrict__ bn2v,
                 const float* __restrict__ wout, const float* __restrict__ bout,
                 float* __restrict__ w9)
{
    __shared__ float stage[8 * NCELLP];   // 38912 B
    __shared__ uint4 x2l[NCELL];          // 19008 B (8 bf16 per cell)
    __shared__ uint4 x1l[TW * TH];        // 16384 B

    const int n = blockIdx.z;
    const int ty = blockIdx.y * TH, tx = blockIdx.x * TW;
    const int tid = threadIdx.x;
    const int wave = tid >> 6, lane = tid & 63;
    const float* xn = x + (size_t)n * CIN * NPIX;

    float acc[3][16];
    #pragma unroll
    for (int o = 0; o < 8; ++o) {
        float b = b1[o];
        acc[0][o] = b; acc[1][o] = b; acc[2][o] = b;
    }
    #pragma unroll
    for (int o = 0; o < 8; ++o) {
        float b = b2[o];
        acc[0][8 + o] = b; acc[1][8 + o] = b; acc[2][8 + o] = b;
    }

    const int cA = tid, cB = tid + 512, cC = tid + 1024;
    const int cCc = (cC < NCELL) ? cC : 0;

    for (int c0 = 0; c0 < 64; c0 += 8) {
        if (c0) __syncthreads();   // previous chunk's LDS reads complete
        // stage 8 channels x halo cells (async, direct-to-LDS)
        for (int t = wave; t < 152; t += 8) {
            int cc = t / 19, r = t - cc * 19;
            int cell = r * 64 + lane;
            if (cell < NCELL) {
                int hy = cell / 66, hx = cell - hy * 66;
                int gy = refl(ty + hy - 1, HH), gx = refl(tx + hx - 1, WW);
                gload_lds4(xn + (size_t)(c0 + cc) * NPIX + gy * WW + gx,
                           &stage[cc * NCELLP + r * 64]);
            }
        }
        __syncthreads();           // staging complete (vmcnt drained)

        float xv[3][8];
        #pragma unroll
        for (int j = 0; j < 8; ++j) {
            xv[0][j] = stage[j * NCELLP + cA];
            xv[1][j] = stage[j * NCELLP + cB];
            xv[2][j] = stage[j * NCELLP + cCc];
        }
        #pragma unroll
        for (int o = 0; o < 16; ++o) {
            const float* wr = (o < 8) ? (w1 + o * CIN + c0) : (w2 + (o - 8) * CIN + c0);
            #pragma unroll
            for (int j = 0; j < 8; ++j) {
                float wj = wr[j];
                acc[0][o] = fmaf(wj, xv[0][j], acc[0][o]);
                acc[1][o] = fmaf(wj, xv[1][j], acc[1][o]);
                acc[2][o] = fmaf(wj, xv[2][j], acc[2][o]);
            }
        }
    }

    // write x1 (interior only) / x2 (all halo cells) to LDS as bf16
    #pragma unroll
    for (int ci = 0; ci < 3; ++ci) {
        int cell = tid + ci * 512;
        if (cell < NCELL) {
            uint4 v2;
            v2.x = bfpack(acc[ci][8],  acc[ci][9]);
            v2.y = bfpack(acc[ci][10], acc[ci][11]);
            v2.z = bfpack(acc[ci][12], acc[ci][13]);
            v2.w = bfpack(acc[ci][14], acc[ci][15]);
            x2l[cell] = v2;
            int hy = cell / 66, hx = cell - hy * 66;
            if (hy >= 1 && hy <= TH && hx >= 1 && hx <= TW) {
                uint4 v1;
                v1.x = bfpack(acc[ci][0], acc[ci][1]);
                v1.y = bfpack(acc[ci][2], acc[ci][3]);
                v1.z = bfpack(acc[ci][4], acc[ci][5]);
                v1.w = bfpack(acc[ci][6], acc[ci][7]);
                x1l[(hy - 1) * TW + (hx - 1)] = v1;
            }
        }
    }
    __syncthreads();

    // fold BN params
    float s1[10], o1[10];
    #pragma unroll
    for (int c = 0; c < 10; ++c) {
        float s = bn1g[c] * rsqrtf(bn1v[c] + 1e-5f);
        s1[c] = s;
        o1[c] = bn1b[c] - bn1m[c] * s;
    }
    float s2[8], o2[8];
    #pragma unroll
    for (int e = 0; e < 8; ++e) {
        float s = bn2g[e] * rsqrtf(bn2v[e] + 1e-5f);
        s2[e] = s;
        o2[e] = bn2b[e] - bn2m[e] * s;
    }
    const float cp00 = cpw[0], cp01 = cpw[1], cp10 = cpw[2], cp11 = cpw[3];
    const float bo = bout[0];

    // MLP + softmax, 2 pixels per thread
    #pragma unroll
    for (int pi = 0; pi < 2; ++pi) {
        int px = tid + pi * 512;
        int py = px >> 6, pxx = px & 63;
        int h = ty + py, w = tx + pxx;
        int cell = (py + 1) * 66 + (pxx + 1);
        uint4 v1 = x1l[px];
        float x1v[8];
        x1v[0] = bflo(v1.x); x1v[1] = bfhi(v1.x);
        x1v[2] = bflo(v1.y); x1v[3] = bfhi(v1.y);
        x1v[4] = bflo(v1.z); x1v[5] = bfhi(v1.z);
        x1v[6] = bflo(v1.w); x1v[7] = bfhi(v1.w);
        float lg[9];
        #pragma unroll
        for (int k = 0; k < 9; ++k) {
            int dy = k / 3 - 1, dx = k % 3 - 1;
            uint4 v2 = x2l[cell + dy * 66 + dx];
            float f[10];
            f[0] = x1v[0] - bflo(v2.x); f[1] = x1v[1] - bfhi(v2.x);
            f[2] = x1v[2] - bflo(v2.y); f[3] = x1v[3] - bfhi(v2.y);
            f[4] = x1v[4] - bflo(v2.z); f[5] = x1v[5] - bfhi(v2.z);
            f[6] = x1v[6] - bflo(v2.w); f[7] = x1v[7] - bfhi(v2.w);
            int hn = refl(h + dy, HH), wn = refl(w + dx, WW);
            float dp0 = (2.0f / 255.0f) * (float)(w - wn);
            float dp1 = (2.0f / 255.0f) * (float)(h - hn);
            f[8] = cp00 * dp0 + cp01 * dp1;
            f[9] = cp10 * dp0 + cp11 * dp1;
            float a[10];
            #pragma unroll
            for (int c = 0; c < 10; ++c)
                a[c] = fmaxf(fmaf(f[c], s1[c], o1[c]), 0.0f);
            float lgk = bo;
            #pragma unroll
            for (int e = 0; e < 8; ++e) {
                float g = 0.0f;
                #pragma unroll
                for (int c = 0; c < 10; ++c) g = fmaf(wmid[e * 10 + c], a[c], g);
                g = fmaxf(fmaf(g, s2[e], o2[e]), 0.0f);
                lgk = fmaf(wout[e], g, lgk);
            }
            lg[k] = lgk;
        }
        float m = lg[0];
        #pragma unroll
        for (int k = 1; k < 9; ++k) m = fmaxf(m, lg[k]);
        float e9[9], ssum = 0.0f;
        #pragma unroll
        for (int k = 0; k < 9; ++k) { e9[k] = __expf(lg[k] - m); ssum += e9[k]; }
        float inv = 1.0f / ssum;
        size_t base = (size_t)n * 9 * NPIX + (size_t)h * WW + w;
        #pragma unroll
        for (int k = 0; k < 9; ++k) w9[base + (size_t)k * NPIX] = e9[k] * inv;
    }
}

// ---------------------------------------------------------------------------
// Kernel 2: s_c = sum_k w_k * x_c[p+dk]; out = W3 @ s + b3
// MFMA split-bf16 channel mix (exact: wh@[sh;sl] + wl@[sh;sl]).
// v3: 512 threads / 8 waves -> 256 regs/wave budget (launch_bounds(512,2)),
// fixing rounds 2/4 where 1024-thread blocks hard-capped 128 regs/wave and
// acc[64]+temps spilled ~1 KB/thread to scratch (FETCH/WRITE blowup).
// Each wave owns 2 rows; acc[2][4][4] f32x4 = 128 AGPR + ~70 arch VGPR < 256.
// Single-buffered staging (compute is tiny now; transfer-bound either way);
// wh AND wl A-fragments precomputed in LDS. Fragment math identical to the
// correctness-verified rounds 2/4.
// ---------------------------------------------------------------------------
__global__ __launch_bounds__(512, 2)
void san_agg(const float* __restrict__ x, const float* __restrict__ w9,
             const float* __restrict__ w3, const float* __restrict__ b3,
             float* __restrict__ out)
{
    __shared__ float buf[16 * NCELLP2];   // 76544 B
    __shared__ uint4 whf[4][4][32];       // 8192 B
    __shared__ uint4 wlf[4][4][32];       // 8192 B   (total 92928 B)

    const int nb = blockIdx.z;
    const int ty = blockIdx.y * TH, tx = blockIdx.x * TW;
    const int tid = threadIdx.x;
    const int wave = tid >> 6, lane = tid & 63;
    const int q = lane >> 4, nn = lane & 15;
    const int oct = q & 1;        // which 8-channel octet of the chunk this lane owns
    const int half = lane >> 5;   // 0: owns even pixel-group, 1: odd
    const float* xn = x + (size_t)nb * CIN * NPIX;

    auto stage = [&](int ch0) {
        for (int t = wave; t < 304; t += 8) {
            int cc = t / 19, r = t - cc * 19;
            int cell = r * 64 + lane;
            if (cell < NCELL) {
                int hy = cell / 66, hx = cell - hy * 66;
                int gy = refl(ty + hy - 1, HH), gx = refl(tx + hx - 1, WW);
                gload_lds4(xn + (size_t)(ch0 + cc) * NPIX + gy * WW + gx,
                           &buf[cc * NCELLP2 + r * 64]);
            }
        }
    };

    // pre-pack wh/wl A-fragments as uint4: entry [kc][mt][l2] covers
    // row m = mt*16 + (l2&15), cols kc*16 + (l2>>4)*8 + {0..7}
    {
        int kcp = tid >> 7, mtp = (tid >> 5) & 3, l2 = tid & 31;
        int m = mtp * 16 + (l2 & 15);
        int c0 = kcp * 16 + (l2 >> 4) * 8;
        const float* wr = w3 + m * 64 + c0;
        float4 wa = *(const float4*)wr;
        float4 wb = *(const float4*)(wr + 4);
        uint4 e;
        e.x = pack2t(wa.x, wa.y); e.y = pack2t(wa.z, wa.w);
        e.z = pack2t(wb.x, wb.y); e.w = pack2t(wb.z, wb.w);
        whf[kcp][mtp][l2] = e;
        uint4 f;
        f.x = pack2t(wa.x - bftrunc(wa.x), wa.y - bftrunc(wa.y));
        f.y = pack2t(wa.z - bftrunc(wa.z), wa.w - bftrunc(wa.w));
        f.z = pack2t(wb.x - bftrunc(wb.x), wb.y - bftrunc(wb.y));
        f.w = pack2t(wb.z - bftrunc(wb.z), wb.w - bftrunc(wb.w));
        wlf[kcp][mtp][l2] = f;
    }

    // attention weights for this wave's 2 rows x 2 owned pixels (bf16-packed)
    u32 wk2p[2][9];
    #pragma unroll
    for (int r = 0; r < 2; ++r) {
        const int h = ty + 2 * wave + r;
        int xw0 = half * 16 + nn;          // s = 0 pixel
        int xw1 = (2 + half) * 16 + nn;    // s = 1 pixel
        size_t wb = (size_t)nb * 9 * NPIX + (size_t)h * WW + tx;
        #pragma unroll
        for (int k = 0; k < 9; ++k)
            wk2p[r][k] = bfpack(w9[wb + (size_t)k * NPIX + xw0],
                                w9[wb + (size_t)k * NPIX + xw1]);
    }

    // accumulators: C row = q*4+j (out channel within mt), col = nn (pixel)
    f32x4 acc[2][4][4];
    #pragma unroll
    for (int mt = 0; mt < 4; ++mt) {
        #pragma unroll
        for (int j = 0; j < 4; ++j) {
            float bv = b3[mt * 16 + q * 4 + j];
            #pragma unroll
            for (int pg = 0; pg < 4; ++pg) {
                acc[0][mt][pg][j] = bv;
                acc[1][mt][pg][j] = bv;
            }
        }
    }

    for (int kc = 0; kc < 4; ++kc) {
        if (kc) __syncthreads();   // prior chunk's buf reads complete
        stage(kc * 16);
        __syncthreads();           // staged (vmcnt drained) + whf/wlf visible

        #pragma unroll
        for (int r = 0; r < 2; ++r) {
            #pragma unroll
            for (int s = 0; s < 2; ++s) {
                float wkf[9];
                #pragma unroll
                for (int k = 0; k < 9; ++k)
                    wkf[k] = (s == 0) ? bflo(wk2p[r][k]) : bfhi(wk2p[r][k]);

                // 9-tap aggregation, this lane's 8 channels, pixel group 2s+half
                const float* cb = buf + oct * 8 * NCELLP2
                                + (2 * wave + r + 1) * 66
                                + (2 * s + half) * 16 + nn + 1;
                float sv[8];
                #pragma unroll
                for (int j = 0; j < 8; ++j) {
                    const float* p = cb + j * NCELLP2;
                    float t = wkf[0] * p[-67];
                    t = fmaf(wkf[1], p[-66], t);
                    t = fmaf(wkf[2], p[-65], t);
                    t = fmaf(wkf[3], p[-1],  t);
                    t = fmaf(wkf[4], p[0],   t);
                    t = fmaf(wkf[5], p[1],   t);
                    t = fmaf(wkf[6], p[65],  t);
                    t = fmaf(wkf[7], p[66],  t);
                    t = fmaf(wkf[8], p[67],  t);
                    sv[j] = t;
                }

                // B-fragments for pixel groups 2s, 2s+1: K=32 = [sh(16ch); sl(16ch)]
                u32 frag2[2][4];
                #pragma unroll
                for (int rr = 0; rr < 4; ++rr) {
                    float a = sv[2 * rr], b = sv[2 * rr + 1];
                    u32 sh = pack2t(a, b);
                    u32 sl = pack2t(a - bftrunc(a), b - bftrunc(b));
                    u32 shx = __shfl_xor(sh, 32);
                    u32 slx = __shfl_xor(sl, 32);
                    frag2[0][rr] = (half == 0) ? sh  : slx;  // pixel group 2s
                    frag2[1][rr] = (half == 0) ? shx : sl;   // pixel group 2s+1
                }

                // channel mix on matrix cores
                #pragma unroll
                for (int mt = 0; mt < 4; ++mt) {
                    uint4 whv = whf[kc][mt][lane & 31];
                    uint4 wlv = wlf[kc][mt][lane & 31];
                    FR wh, wl;
                    wh.u[0] = whv.x; wh.u[1] = whv.y; wh.u[2] = whv.z; wh.u[3] = whv.w;
                    wl.u[0] = wlv.x; wl.u[1] = wlv.y; wl.u[2] = wlv.z; wl.u[3] = wlv.w;
                    #pragma unroll
                    for (int h2 = 0; h2 < 2; ++h2) {
                        FR bfr;
                        bfr.u[0] = frag2[h2][0]; bfr.u[1] = frag2[h2][1];
                        bfr.u[2] = frag2[h2][2]; bfr.u[3] = frag2[h2][3];
                        acc[r][mt][2 * s + h2] = __builtin_amdgcn_mfma_f32_16x16x32_bf16(
                            wh.s, bfr.s, acc[r][mt][2 * s + h2], 0, 0, 0);
                        acc[r][mt][2 * s + h2] = __builtin_amdgcn_mfma_f32_16x16x32_bf16(
                            wl.s, bfr.s, acc[r][mt][2 * s + h2], 0, 0, 0);
                    }
                }
            }
        }
    }

    // store: channel m = mt*16 + q*4 + j, pixel x = pg*16 + nn, row = 2*wave+r
    #pragma unroll
    for (int r = 0; r < 2; ++r) {
        const int h = ty + 2 * wave + r;
        size_t ob = (size_t)nb * CIN * NPIX + (size_t)h * WW + tx;
        #pragma unroll
        for (int mt = 0; mt < 4; ++mt) {
            #pragma unroll
            for (int pg = 0; pg < 4; ++pg) {
                size_t pb = ob + (size_t)pg * 16 + nn;
                #pragma unroll
                for (int j = 0; j < 4; ++j) {
                    int m = mt * 16 + q * 4 + j;
                    out[pb + (size_t)m * NPIX] = acc[r][mt][pg][j];
                }
            }
        }
    }
}

// ---------------------------------------------------------------------------
extern "C" void kernel_launch(void* const* d_in, const int* in_sizes, int n_in,
                              void* d_out, int out_size, void* d_ws, size_t ws_size,
                              hipStream_t stream) {
    const float* x      = (const float*)d_in[0];
    const float* w1     = (const float*)d_in[1];
    const float* b1     = (const float*)d_in[2];
    const float* w2     = (const float*)d_in[3];
    const float* b2     = (const float*)d_in[4];
    const float* w3     = (const float*)d_in[5];
    const float* b3     = (const float*)d_in[6];
    const float* cpw    = (const float*)d_in[7];
    const float* bn1g   = (const float*)d_in[9];
    const float* bn1b   = (const float*)d_in[10];
    const float* bn1m   = (const float*)d_in[11];
    const float* bn1v   = (const float*)d_in[12];
    const float* wmid   = (const float*)d_in[13];
    const float* bn2g   = (const float*)d_in[14];
    const float* bn2b   = (const float*)d_in[15];
    const float* bn2m   = (const float*)d_in[16];
    const float* bn2v   = (const float*)d_in[17];
    const float* wout   = (const float*)d_in[18];
    const float* bout   = (const float*)d_in[19];
    float* out = (float*)d_out;
    float* w9  = (float*)d_ws;  // 16*9*65536 floats = 37.75 MB

    dim3 grid(WW / TW, HH / TH, 16);
    san_weights<<<grid, 512, 0, stream>>>(x, w1, b1, w2, b2, cpw,
                                          bn1g, bn1b, bn1m, bn1v, wmid,
                                          bn2g, bn2b, bn2m, bn2v, wout, bout, w9);
    san_agg<<<grid, 512, 0, stream>>>(x, w9, w3, b3, out);
}